// Round 2
// baseline (712.167 us; speedup 1.0000x reference)
//
#include <hip/hip_runtime.h>

using short8 = __attribute__((ext_vector_type(8))) short;
using fx4    = __attribute__((ext_vector_type(4))) float;

#define NB 8
#define CDIM 256
#define HH 128
#define NPIX 16384
#define NG_ELEMS 131072.0f

__device__ __forceinline__ float bf2f(short s) {
    union { unsigned u; float f; } c; c.u = ((unsigned)(unsigned short)s) << 16; return c.f;
}
__device__ __forceinline__ short f2bf(float f) {
    union { float f; unsigned u; } c; c.f = f;
    unsigned u = c.u;
    u += 0x7FFFu + ((u >> 16) & 1u);
    return (short)(u >> 16);
}

// ---------------- Kernel G: fused transpose + GEMM (fp32 in, bf16 out) + group stats ----
// qt[b][pix][o] = X[b][:, pix] . W[o][:]   (X fp32 [b][c][pix], W fp32 [o][c])
__global__ __launch_bounds__(256) void kG(const float* __restrict__ xlo,
                                          const float* __restrict__ xhi,
                                          const float* __restrict__ wq,
                                          const float* __restrict__ wk,
                                          short* __restrict__ qt,
                                          short* __restrict__ kt,
                                          float* __restrict__ stats) {
    // MFMA fragment order, 16B granules; A granules XOR-swizzled: phys = gl ^ tile
    __shared__ short As[8 * 64 * 8];
    __shared__ short Bs[8 * 64 * 8];
    int m_blk = blockIdx.x;           // 0..127  pixel tiles of 128
    int n_blk = blockIdx.y;           // 0..1    out-channel tiles of 128
    int z = blockIdx.z;               // 0..15
    int b = z >> 1, t = z & 1;
    const float* X = (t ? xhi : xlo) + (size_t)b * CDIM * NPIX;
    const float* W = t ? wk : wq;
    short* OUT = (t ? kt : qt) + (size_t)b * NPIX * CDIM;
    int m0 = m_blk * 128, n0 = n_blk * 128;
    int tid = threadIdx.x;
    int w = tid >> 6, l = tid & 63, lr = l & 15, quad = l >> 4;
    int mh = w >> 1, nh = w & 1;

    // A-staging mapping: thread -> (channel row cr in slice, 16 consecutive pixels)
    int cr   = tid >> 3;              // 0..31
    int tileA = tid & 7;              // pixel tile (16 pixels each)
    int aq16 = (cr >> 3) * 16;        // c-octet * 16 (read-lane quad group)
    int jjA  = cr & 7;                // element index within fragment
    const float* abase = X + (size_t)cr * NPIX + m0 + tileA * 16;
    int awbase = (tileA * 64 + aq16) * 8 + jjA;

    // B-staging: thread stages 2 weight rows in fragment order (c-contiguous already)
    const float* brow0 = W + (size_t)(n0 + (2 * w) * 16 + lr) * CDIM + quad * 8;
    const float* brow1 = brow0 + 16 * CDIM;

    fx4 acc[4][4];
#pragma unroll
    for (int i = 0; i < 4; ++i)
#pragma unroll
        for (int j = 0; j < 4; ++j) { acc[i][j][0]=0.f; acc[i][j][1]=0.f; acc[i][j][2]=0.f; acc[i][j][3]=0.f; }

    for (int kc = 0; kc < 8; ++kc) {
        const float* ap = abase + (size_t)kc * 32 * NPIX;
        fx4 a0 = *(const fx4*)(ap);
        fx4 a1 = *(const fx4*)(ap + 4);
        fx4 a2 = *(const fx4*)(ap + 8);
        fx4 a3 = *(const fx4*)(ap + 12);
        fx4 b00 = *(const fx4*)(brow0 + kc * 32);
        fx4 b01 = *(const fx4*)(brow0 + kc * 32 + 4);
        fx4 b10 = *(const fx4*)(brow1 + kc * 32);
        fx4 b11 = *(const fx4*)(brow1 + kc * 32 + 4);
        __syncthreads();
        // A: 16 scalar b16 writes, bank-spread by (e ^ tileA)
#pragma unroll
        for (int e = 0; e < 4; ++e) {
            As[awbase + ((e +  0) ^ tileA) * 8] = f2bf(a0[e]);
            As[awbase + ((e +  4) ^ tileA) * 8] = f2bf(a1[e]);
            As[awbase + ((e +  8) ^ tileA) * 8] = f2bf(a2[e]);
            As[awbase + ((e + 12) ^ tileA) * 8] = f2bf(a3[e]);
        }
        short8 s0, s1;
#pragma unroll
        for (int e = 0; e < 4; ++e) {
            s0[e] = f2bf(b00[e]); s0[4 + e] = f2bf(b01[e]);
            s1[e] = f2bf(b10[e]); s1[4 + e] = f2bf(b11[e]);
        }
        *(short8*)(&Bs[((2 * w)     * 64 + l) * 8]) = s0;
        *(short8*)(&Bs[((2 * w + 1) * 64 + l) * 8]) = s1;
        __syncthreads();
        short8 af[4], bf[4];
#pragma unroll
        for (int i = 0; i < 4; ++i) {
            int tile = mh * 4 + i;
            af[i] = *(const short8*)(&As[(tile * 64 + (l ^ tile)) * 8]);
        }
#pragma unroll
        for (int j = 0; j < 4; ++j)
            bf[j] = *(const short8*)(&Bs[((nh * 4 + j) * 64 + l) * 8]);
#pragma unroll
        for (int i = 0; i < 4; ++i)
#pragma unroll
            for (int j = 0; j < 4; ++j)
                acc[i][j] = __builtin_amdgcn_mfma_f32_16x16x32_bf16(af[i], bf[j], acc[i][j], 0, 0, 0);
    }

    // group stats: per-column sums, quad-reduce then octet-reduce, 2 atomics per group
#pragma unroll
    for (int j = 0; j < 4; ++j) {
        float s = 0.f, ss = 0.f;
#pragma unroll
        for (int i = 0; i < 4; ++i)
#pragma unroll
            for (int r = 0; r < 4; ++r) { float v = acc[i][j][r]; s += v; ss += v * v; }
        s += __shfl_xor(s, 16); ss += __shfl_xor(ss, 16);
        s += __shfl_xor(s, 32); ss += __shfl_xor(ss, 32);
        s += __shfl_xor(s, 1);  ss += __shfl_xor(ss, 1);
        s += __shfl_xor(s, 2);  ss += __shfl_xor(ss, 2);
        s += __shfl_xor(s, 4);  ss += __shfl_xor(ss, 4);
        if (l == 0 || l == 8) {
            int o = n0 + (nh * 4 + j) * 16 + (l & 15);
            int g = o >> 3;
            float* st = stats + ((size_t)(t * NB + b) * 32 + g) * 2;
            atomicAdd(st, s);
            atomicAdd(st + 1, ss);
        }
    }

    // store bf16 [pix][o]
#pragma unroll
    for (int i = 0; i < 4; ++i) {
        int pix = m0 + (mh * 4 + i) * 16 + quad * 4;
#pragma unroll
        for (int j = 0; j < 4; ++j) {
            int o = n0 + (nh * 4 + j) * 16 + lr;
#pragma unroll
            for (int r = 0; r < 4; ++r)
                OUT[(size_t)(pix + r) * CDIM + o] = f2bf(acc[i][j][r]);
        }
    }
}

// ---------------- Kernel S: stats -> per-(tensor,b,o) scale/shift (fp32 params) --------
__global__ __launch_bounds__(256) void kS(const float* __restrict__ stats,
                                          const float* __restrict__ gq,
                                          const float* __restrict__ bq,
                                          const float* __restrict__ gk,
                                          const float* __restrict__ bk,
                                          float* __restrict__ scale,
                                          float* __restrict__ shift) {
    int id = blockIdx.x * 256 + threadIdx.x;   // 0..4095
    int t = id >> 11, b = (id >> 8) & 7, o = id & 255;
    int g = o >> 3;
    const float* st = stats + ((size_t)(t * NB + b) * 32 + g) * 2;
    float mean = st[0] * (1.0f / NG_ELEMS);
    float var  = st[1] * (1.0f / NG_ELEMS) - mean * mean;
    float rstd = rsqrtf(var + 1e-5f);
    float gamma = (t ? gk : gq)[o];
    float beta  = (t ? bk : bq)[o];
    float sc = gamma * rstd;
    scale[id] = sc;
    shift[id] = beta - mean * sc;
}

// ---------------- Kernel A: windowed attention + fp32 residual/output ------------------
__global__ __launch_bounds__(256) void kA(const short* __restrict__ qt,
                                          const short* __restrict__ kt,
                                          const float* __restrict__ scale,
                                          const float* __restrict__ shift,
                                          const float* __restrict__ xlo,
                                          float* __restrict__ outp) {
    __shared__ short Ks[64 * 264];     // normalized K window [j][c], pad 8
    __shared__ float SsF[64 * 68];     // scores fp32; later reused as Os (short, stride 136)
    __shared__ short Ps[64 * 72];      // softmax probs bf16 [i][j], pad 8
    short* Os = (short*)SsF;

    int blk = blockIdx.x;              // 0..2047
    int b = blk >> 8, wh = (blk >> 4) & 15, ww = blk & 15;
    int tid = threadIdx.x;
    int w = tid >> 6, l = tid & 63, lr = l & 15, quad = l >> 4;

    const float* sq = scale + (size_t)b * CDIM;
    const float* zq = shift + (size_t)b * CDIM;
    const float* sk = scale + (size_t)(NB + b) * CDIM;
    const float* zk = shift + (size_t)(NB + b) * CDIM;

    // build normalized K window in LDS
    {
        int oct = tid & 31;
        int j00 = tid >> 5;
        float skv[8], zkv[8];
#pragma unroll
        for (int e = 0; e < 8; ++e) { skv[e] = sk[oct * 8 + e]; zkv[e] = zk[oct * 8 + e]; }
#pragma unroll
        for (int it = 0; it < 8; ++it) {
            int j = j00 + it * 8;
            int pix = (wh * 8 + (j >> 3)) * HH + ww * 8 + (j & 7);
            short8 kv = *(const short8*)(kt + ((size_t)b * NPIX + pix) * CDIM + oct * 8);
            short8 nv;
#pragma unroll
            for (int e = 0; e < 8; ++e) nv[e] = f2bf(bf2f(kv[e]) * skv[e] + zkv[e]);
            *(short8*)(&Ks[j * 264 + oct * 8]) = nv;
        }
    }
    __syncthreads();

    // S = Qn @ Kn^T / 16 ; wave w computes rows [16w,16w+16)
    {
        fx4 accS[4];
#pragma unroll
        for (int nt = 0; nt < 4; ++nt) { accS[nt][0]=0.f; accS[nt][1]=0.f; accS[nt][2]=0.f; accS[nt][3]=0.f; }
        int qi = 16 * w + lr;
        int pixq = (wh * 8 + (qi >> 3)) * HH + ww * 8 + (qi & 7);
        const short* qrow = qt + ((size_t)b * NPIX + pixq) * CDIM;
#pragma unroll
        for (int kc = 0; kc < 8; ++kc) {
            int c0 = kc * 32 + quad * 8;
            short8 qv = *(const short8*)(qrow + c0);
            short8 aq;
#pragma unroll
            for (int e = 0; e < 8; ++e) aq[e] = f2bf(bf2f(qv[e]) * sq[c0 + e] + zq[c0 + e]);
#pragma unroll
            for (int nt = 0; nt < 4; ++nt) {
                short8 bk8 = *(const short8*)(&Ks[(nt * 16 + lr) * 264 + c0]);
                accS[nt] = __builtin_amdgcn_mfma_f32_16x16x32_bf16(aq, bk8, accS[nt], 0, 0, 0);
            }
        }
#pragma unroll
        for (int nt = 0; nt < 4; ++nt)
#pragma unroll
            for (int r = 0; r < 4; ++r)
                SsF[(16 * w + quad * 4 + r) * 68 + nt * 16 + lr] = accS[nt][r] * 0.0625f;
    }
    __syncthreads();

    // softmax over rows (4 threads per row)
    {
        int row = tid >> 2, seg = tid & 3;
        float v[16];
#pragma unroll
        for (int k4 = 0; k4 < 4; ++k4) {
            fx4 t4 = *(const fx4*)(&SsF[row * 68 + seg * 16 + k4 * 4]);
            v[k4*4+0] = t4[0]; v[k4*4+1] = t4[1]; v[k4*4+2] = t4[2]; v[k4*4+3] = t4[3];
        }
        float m = v[0];
#pragma unroll
        for (int e = 1; e < 16; ++e) m = fmaxf(m, v[e]);
        m = fmaxf(m, __shfl_xor(m, 1));
        m = fmaxf(m, __shfl_xor(m, 2));
        float s = 0.f;
#pragma unroll
        for (int e = 0; e < 16; ++e) { v[e] = __expf(v[e] - m); s += v[e]; }
        s += __shfl_xor(s, 1);
        s += __shfl_xor(s, 2);
        float inv = 1.0f / s;
        short8 p0, p1;
#pragma unroll
        for (int e = 0; e < 8; ++e) { p0[e] = f2bf(v[e] * inv); p1[e] = f2bf(v[8 + e] * inv); }
        *(short8*)(&Ps[row * 72 + seg * 16]) = p0;
        *(short8*)(&Ps[row * 72 + seg * 16 + 8]) = p1;
    }
    __syncthreads();

    // O = P @ Kn ; wave w computes channels [64w, 64w+64)
    fx4 accO[4][4];
#pragma unroll
    for (int mt = 0; mt < 4; ++mt)
#pragma unroll
        for (int nt = 0; nt < 4; ++nt) { accO[mt][nt][0]=0.f; accO[mt][nt][1]=0.f; accO[mt][nt][2]=0.f; accO[mt][nt][3]=0.f; }
#pragma unroll
    for (int kc2 = 0; kc2 < 2; ++kc2) {
        int j0 = kc2 * 32 + quad * 8;
        short8 ap[4];
#pragma unroll
        for (int mt = 0; mt < 4; ++mt)
            ap[mt] = *(const short8*)(&Ps[(mt * 16 + lr) * 72 + j0]);
#pragma unroll
        for (int nt = 0; nt < 4; ++nt) {
            int c = 64 * w + nt * 16 + lr;
            short8 bk8;
#pragma unroll
            for (int jj = 0; jj < 8; ++jj) bk8[jj] = Ks[(j0 + jj) * 264 + c];
#pragma unroll
            for (int mt = 0; mt < 4; ++mt)
                accO[mt][nt] = __builtin_amdgcn_mfma_f32_16x16x32_bf16(ap[mt], bk8, accO[mt][nt], 0, 0, 0);
        }
    }

    // epilogue in two halves (Os overlays Ss region), transposed, fp32 residual + store
    int half = w >> 1;
#pragma unroll
    for (int h2 = 0; h2 < 2; ++h2) {
        __syncthreads();
        if (half == h2) {
#pragma unroll
            for (int mt = 0; mt < 4; ++mt)
#pragma unroll
                for (int nt = 0; nt < 4; ++nt) {
                    int i = mt * 16 + quad * 4;
                    int cl = 64 * w + nt * 16 + lr - 128 * h2;   // 0..127
#pragma unroll
                    for (int r = 0; r < 4; ++r)
                        Os[(i + r) * 136 + cl] = f2bf(accO[mt][nt][r]);
                }
        }
        __syncthreads();
#pragma unroll
        for (int it = 0; it < 4; ++it) {
            int id = tid + it * 256;
            int cl = id & 127, h = id >> 7;   // h 0..7
            int cg = cl + 128 * h2;
            size_t gidx = ((size_t)(b * CDIM + cg)) * NPIX + (size_t)(wh * 8 + h) * HH + ww * 8;
            fx4 x0 = *(const fx4*)(xlo + gidx);
            fx4 x1 = *(const fx4*)(xlo + gidx + 4);
            fx4 r0, r1;
#pragma unroll
            for (int jj = 0; jj < 4; ++jj) {
                r0[jj] = bf2f(Os[(h * 8 + jj)     * 136 + cl]) + x0[jj];
                r1[jj] = bf2f(Os[(h * 8 + 4 + jj) * 136 + cl]) + x1[jj];
            }
            *(fx4*)(outp + gidx)     = r0;
            *(fx4*)(outp + gidx + 4) = r1;
        }
    }
}

extern "C" void kernel_launch(void* const* d_in, const int* in_sizes, int n_in,
                              void* d_out, int out_size, void* d_ws, size_t ws_size,
                              hipStream_t stream) {
    const float* xlo = (const float*)d_in[0];
    const float* xhi = (const float*)d_in[1];
    const float* wqp = (const float*)d_in[2];
    const float* wkp = (const float*)d_in[3];
    const float* gq  = (const float*)d_in[4];
    const float* bq  = (const float*)d_in[5];
    const float* gk  = (const float*)d_in[6];
    const float* bk  = (const float*)d_in[7];
    float* outp = (float*)d_out;
    char* ws = (char*)d_ws;
    size_t SZB = (size_t)NB * NPIX * CDIM * 2;   // 64 MB per bf16 tensor
    short* qt = (short*)(ws);
    short* kt = (short*)(ws + SZB);
    float* stats = (float*)(ws + 2 * SZB);
    float* scale = (float*)(ws + 2 * SZB + 4096);
    float* shift = (float*)(ws + 2 * SZB + 4096 + 16384);

    hipMemsetAsync(stats, 0, 4096, stream);
    kG<<<dim3(128, 2, 16), dim3(256), 0, stream>>>(xlo, xhi, wqp, wkp, qt, kt, stats);
    kS<<<dim3(16), dim3(256), 0, stream>>>(stats, gq, bq, gk, bk, scale, shift);
    kA<<<dim3(2048), dim3(256), 0, stream>>>(qt, kt, scale, shift, xlo, outp);
}

// Round 3
// 624.590 us; speedup vs baseline: 1.1402x; 1.1402x over previous
//
#include <hip/hip_runtime.h>
#include <hip/hip_bf16.h>

using short8 = __attribute__((ext_vector_type(8))) short;
using fx4    = __attribute__((ext_vector_type(4))) float;

#define NB 8
#define CDIM 256
#define HH 128
#define NPIX 16384
#define NG_ELEMS 131072.0f

__device__ __forceinline__ float bf2f(short s) {
    union { unsigned u; float f; } c; c.u = ((unsigned)(unsigned short)s) << 16; return c.f;
}
__device__ __forceinline__ short f2bf(float f) {
    union { float f; unsigned u; } c; c.f = f;
    unsigned u = c.u;
    u += 0x7FFFu + ((u >> 16) & 1u);
    return (short)(u >> 16);
}
// packed RTNE fp32x2 -> bf16x2 (v_cvt_pk_bf16_f32 on gfx950)
__device__ __forceinline__ short2 f2bf2(float a, float b) {
    __hip_bfloat162 h = __float22bfloat162_rn(make_float2(a, b));
    union { __hip_bfloat162 b; short2 s; } c; c.b = h; return c.s;
}

// ---------------- Kernel W: wq/wk fp32 -> bf16 in MFMA B-fragment order ----------------
// WB[t][kc(8)][ntile(16)][lane(64)][8el]
__global__ __launch_bounds__(256) void kW(const float* __restrict__ wq,
                                          const float* __restrict__ wk,
                                          short* __restrict__ WB) {
    int kc = blockIdx.x;      // 0..7
    int t  = blockIdx.y;      // 0..1
    const float* W = t ? wk : wq;
    int tid = threadIdx.x;
    int ntile = tid >> 4, lr = tid & 15;
    int n = ntile * 16 + lr;
#pragma unroll
    for (int quad = 0; quad < 4; ++quad) {
        const float* p = W + (size_t)n * CDIM + kc * 32 + quad * 8;
        fx4 v0 = *(const fx4*)p;
        fx4 v1 = *(const fx4*)(p + 4);
        union { short8 v; short2 h[4]; } s;
        s.h[0] = f2bf2(v0[0], v0[1]);
        s.h[1] = f2bf2(v0[2], v0[3]);
        s.h[2] = f2bf2(v1[0], v1[1]);
        s.h[3] = f2bf2(v1[2], v1[3]);
        *(short8*)(WB + ((((size_t)t * 8 + kc) * 16 + ntile) * 64 + quad * 16 + lr) * 8) = s.v;
    }
}

// ---------------- Kernel G: barrier-free streaming GEMM + group stats ------------------
// qt[b][pix][o] = X[b][:,pix].W[o][:]; A-frags gathered directly from global (no LDS)
__global__ __launch_bounds__(256, 2) void kG(const float* __restrict__ xlo,
                                             const float* __restrict__ xhi,
                                             const short* __restrict__ WB,
                                             short* __restrict__ qt,
                                             short* __restrict__ kt,
                                             float* __restrict__ stats) {
    int m0 = blockIdx.x * 128;                 // 128 pixels per block
    int zy = blockIdx.y;                       // 0..15
    int b = zy >> 1, t = zy & 1;
    const float* X = (t ? xhi : xlo) + (size_t)b * CDIM * NPIX;
    const short* WBt = WB + (size_t)t * 8 * 16 * 64 * 8;
    short* OUT = (t ? kt : qt) + (size_t)b * NPIX * CDIM;
    int tid = threadIdx.x;
    int w = tid >> 6, l = tid & 63, lr = l & 15, quad = l >> 4;
    int mh = w >> 1, nh = w & 1;               // wave = 64 pix (mh) x 128 out (nh)
    int pixb = m0 + mh * 64 + lr;

    fx4 acc[4][8];
#pragma unroll
    for (int mt = 0; mt < 4; ++mt)
#pragma unroll
        for (int nt = 0; nt < 8; ++nt) { acc[mt][nt][0]=0.f; acc[mt][nt][1]=0.f; acc[mt][nt][2]=0.f; acc[mt][nt][3]=0.f; }

    for (int kc = 0; kc < 8; ++kc) {
        // B fragments: one 16B lane-contiguous load each (L2-hot, pre-converted bf16)
        short8 bf[8];
        const short* wb = WBt + ((size_t)kc * 16 + nh * 8) * 64 * 8 + (size_t)l * 8;
#pragma unroll
        for (int nt = 0; nt < 8; ++nt)
            bf[nt] = *(const short8*)(wb + (size_t)nt * 64 * 8);
        // A fragments: direct strided gather (per inst: 4 rows x 64B contiguous)
        short8 af[4];
        const float* xp = X + (size_t)(kc * 32 + quad * 8) * NPIX + pixb;
#pragma unroll
        for (int mt = 0; mt < 4; ++mt) {
            float e0 = xp[(size_t)0 * NPIX + mt * 16];
            float e1 = xp[(size_t)1 * NPIX + mt * 16];
            float e2 = xp[(size_t)2 * NPIX + mt * 16];
            float e3 = xp[(size_t)3 * NPIX + mt * 16];
            float e4 = xp[(size_t)4 * NPIX + mt * 16];
            float e5 = xp[(size_t)5 * NPIX + mt * 16];
            float e6 = xp[(size_t)6 * NPIX + mt * 16];
            float e7 = xp[(size_t)7 * NPIX + mt * 16];
            union { short8 v; short2 h[4]; } s;
            s.h[0] = f2bf2(e0, e1); s.h[1] = f2bf2(e2, e3);
            s.h[2] = f2bf2(e4, e5); s.h[3] = f2bf2(e6, e7);
            af[mt] = s.v;
        }
#pragma unroll
        for (int mt = 0; mt < 4; ++mt)
#pragma unroll
            for (int nt = 0; nt < 8; ++nt)
                acc[mt][nt] = __builtin_amdgcn_mfma_f32_16x16x32_bf16(af[mt], bf[nt], acc[mt][nt], 0, 0, 0);
    }

    // group stats: per-column sums, butterfly, 2 atomics per group per wave
#pragma unroll
    for (int nt = 0; nt < 8; ++nt) {
        float s = 0.f, ss = 0.f;
#pragma unroll
        for (int mt = 0; mt < 4; ++mt)
#pragma unroll
            for (int r = 0; r < 4; ++r) { float v = acc[mt][nt][r]; s += v; ss += v * v; }
        s += __shfl_xor(s, 16); ss += __shfl_xor(ss, 16);
        s += __shfl_xor(s, 32); ss += __shfl_xor(ss, 32);
        s += __shfl_xor(s, 1);  ss += __shfl_xor(ss, 1);
        s += __shfl_xor(s, 2);  ss += __shfl_xor(ss, 2);
        s += __shfl_xor(s, 4);  ss += __shfl_xor(ss, 4);
        if (l == 0 || l == 8) {
            int o = nh * 128 + nt * 16 + (l & 15);
            int g = o >> 3;
            float* st = stats + ((size_t)(t * NB + b) * 32 + g) * 2;
            atomicAdd(st, s);
            atomicAdd(st + 1, ss);
        }
    }

    // store bf16 [pix][o]
#pragma unroll
    for (int mt = 0; mt < 4; ++mt) {
        int pix = m0 + mh * 64 + mt * 16 + quad * 4;
#pragma unroll
        for (int nt = 0; nt < 8; ++nt) {
            int o = nh * 128 + nt * 16 + lr;
            short2 p0 = f2bf2(acc[mt][nt][0], acc[mt][nt][1]);
            short2 p1 = f2bf2(acc[mt][nt][2], acc[mt][nt][3]);
            OUT[(size_t)(pix + 0) * CDIM + o] = p0.x;
            OUT[(size_t)(pix + 1) * CDIM + o] = p0.y;
            OUT[(size_t)(pix + 2) * CDIM + o] = p1.x;
            OUT[(size_t)(pix + 3) * CDIM + o] = p1.y;
        }
    }
}

// ---------------- Kernel S: stats -> per-(tensor,b,o) scale/shift ----------------------
__global__ __launch_bounds__(256) void kS(const float* __restrict__ stats,
                                          const float* __restrict__ gq,
                                          const float* __restrict__ bq,
                                          const float* __restrict__ gk,
                                          const float* __restrict__ bk,
                                          float* __restrict__ scale,
                                          float* __restrict__ shift) {
    int id = blockIdx.x * 256 + threadIdx.x;   // 0..4095
    int t = id >> 11, b = (id >> 8) & 7, o = id & 255;
    int g = o >> 3;
    const float* st = stats + ((size_t)(t * NB + b) * 32 + g) * 2;
    float mean = st[0] * (1.0f / NG_ELEMS);
    float var  = st[1] * (1.0f / NG_ELEMS) - mean * mean;
    float rstd = rsqrtf(var + 1e-5f);
    float gamma = (t ? gk : gq)[o];
    float beta  = (t ? bk : bq)[o];
    float sc = gamma * rstd;
    scale[id] = sc;
    shift[id] = beta - mean * sc;
}

// ---------------- Kernel A: windowed attention + fp32 residual/output ------------------
__global__ __launch_bounds__(256) void kA(const short* __restrict__ qt,
                                          const short* __restrict__ kt,
                                          const float* __restrict__ scale,
                                          const float* __restrict__ shift,
                                          const float* __restrict__ xlo,
                                          float* __restrict__ outp) {
    __shared__ short Ks[64 * 264];     // normalized K window [j][c], pad 8
    __shared__ float SsF[64 * 68];     // scores fp32; later reused as Os (short, stride 136)
    __shared__ short Ps[64 * 72];      // softmax probs bf16 [i][j], pad 8
    short* Os = (short*)SsF;

    int blk = blockIdx.x;              // 0..2047
    int b = blk >> 8, wh = (blk >> 4) & 15, ww = blk & 15;
    int tid = threadIdx.x;
    int w = tid >> 6, l = tid & 63, lr = l & 15, quad = l >> 4;

    const float* sq = scale + (size_t)b * CDIM;
    const float* zq = shift + (size_t)b * CDIM;
    const float* sk = scale + (size_t)(NB + b) * CDIM;
    const float* zk = shift + (size_t)(NB + b) * CDIM;

    // build normalized K window in LDS
    {
        int oct = tid & 31;
        int j00 = tid >> 5;
        float skv[8], zkv[8];
#pragma unroll
        for (int e = 0; e < 8; ++e) { skv[e] = sk[oct * 8 + e]; zkv[e] = zk[oct * 8 + e]; }
#pragma unroll
        for (int it = 0; it < 8; ++it) {
            int j = j00 + it * 8;
            int pix = (wh * 8 + (j >> 3)) * HH + ww * 8 + (j & 7);
            short8 kv = *(const short8*)(kt + ((size_t)b * NPIX + pix) * CDIM + oct * 8);
            short8 nv;
#pragma unroll
            for (int e = 0; e < 8; ++e) nv[e] = f2bf(bf2f(kv[e]) * skv[e] + zkv[e]);
            *(short8*)(&Ks[j * 264 + oct * 8]) = nv;
        }
    }
    __syncthreads();

    // S = Qn @ Kn^T / 16 ; wave w computes rows [16w,16w+16)
    {
        fx4 accS[4];
#pragma unroll
        for (int nt = 0; nt < 4; ++nt) { accS[nt][0]=0.f; accS[nt][1]=0.f; accS[nt][2]=0.f; accS[nt][3]=0.f; }
        int qi = 16 * w + lr;
        int pixq = (wh * 8 + (qi >> 3)) * HH + ww * 8 + (qi & 7);
        const short* qrow = qt + ((size_t)b * NPIX + pixq) * CDIM;
#pragma unroll
        for (int kc = 0; kc < 8; ++kc) {
            int c0 = kc * 32 + quad * 8;
            short8 qv = *(const short8*)(qrow + c0);
            short8 aq;
#pragma unroll
            for (int e = 0; e < 8; ++e) aq[e] = f2bf(bf2f(qv[e]) * sq[c0 + e] + zq[c0 + e]);
#pragma unroll
            for (int nt = 0; nt < 4; ++nt) {
                short8 bk8 = *(const short8*)(&Ks[(nt * 16 + lr) * 264 + c0]);
                accS[nt] = __builtin_amdgcn_mfma_f32_16x16x32_bf16(aq, bk8, accS[nt], 0, 0, 0);
            }
        }
#pragma unroll
        for (int nt = 0; nt < 4; ++nt)
#pragma unroll
            for (int r = 0; r < 4; ++r)
                SsF[(16 * w + quad * 4 + r) * 68 + nt * 16 + lr] = accS[nt][r] * 0.0625f;
    }
    __syncthreads();

    // softmax over rows (4 threads per row)
    {
        int row = tid >> 2, seg = tid & 3;
        float v[16];
#pragma unroll
        for (int k4 = 0; k4 < 4; ++k4) {
            fx4 t4 = *(const fx4*)(&SsF[row * 68 + seg * 16 + k4 * 4]);
            v[k4*4+0] = t4[0]; v[k4*4+1] = t4[1]; v[k4*4+2] = t4[2]; v[k4*4+3] = t4[3];
        }
        float m = v[0];
#pragma unroll
        for (int e = 1; e < 16; ++e) m = fmaxf(m, v[e]);
        m = fmaxf(m, __shfl_xor(m, 1));
        m = fmaxf(m, __shfl_xor(m, 2));
        float s = 0.f;
#pragma unroll
        for (int e = 0; e < 16; ++e) { v[e] = __expf(v[e] - m); s += v[e]; }
        s += __shfl_xor(s, 1);
        s += __shfl_xor(s, 2);
        float inv = 1.0f / s;
        short8 p0, p1;
#pragma unroll
        for (int e = 0; e < 8; ++e) { p0[e] = f2bf(v[e] * inv); p1[e] = f2bf(v[8 + e] * inv); }
        *(short8*)(&Ps[row * 72 + seg * 16]) = p0;
        *(short8*)(&Ps[row * 72 + seg * 16 + 8]) = p1;
    }
    __syncthreads();

    // O = P @ Kn ; wave w computes channels [64w, 64w+64)
    fx4 accO[4][4];
#pragma unroll
    for (int mt = 0; mt < 4; ++mt)
#pragma unroll
        for (int nt = 0; nt < 4; ++nt) { accO[mt][nt][0]=0.f; accO[mt][nt][1]=0.f; accO[mt][nt][2]=0.f; accO[mt][nt][3]=0.f; }
#pragma unroll
    for (int kc2 = 0; kc2 < 2; ++kc2) {
        int j0 = kc2 * 32 + quad * 8;
        short8 ap[4];
#pragma unroll
        for (int mt = 0; mt < 4; ++mt)
            ap[mt] = *(const short8*)(&Ps[(mt * 16 + lr) * 72 + j0]);
#pragma unroll
        for (int nt = 0; nt < 4; ++nt) {
            int c = 64 * w + nt * 16 + lr;
            short8 bk8;
#pragma unroll
            for (int jj = 0; jj < 8; ++jj) bk8[jj] = Ks[(j0 + jj) * 264 + c];
#pragma unroll
            for (int mt = 0; mt < 4; ++mt)
                accO[mt][nt] = __builtin_amdgcn_mfma_f32_16x16x32_bf16(ap[mt], bk8, accO[mt][nt], 0, 0, 0);
        }
    }

    // epilogue in two halves (Os overlays Ss region), transposed, fp32 residual + store
    int half = w >> 1;
#pragma unroll
    for (int h2 = 0; h2 < 2; ++h2) {
        __syncthreads();
        if (half == h2) {
#pragma unroll
            for (int mt = 0; mt < 4; ++mt)
#pragma unroll
                for (int nt = 0; nt < 4; ++nt) {
                    int i = mt * 16 + quad * 4;
                    int cl = 64 * w + nt * 16 + lr - 128 * h2;   // 0..127
#pragma unroll
                    for (int r = 0; r < 4; ++r)
                        Os[(i + r) * 136 + cl] = f2bf(accO[mt][nt][r]);
                }
        }
        __syncthreads();
#pragma unroll
        for (int it = 0; it < 4; ++it) {
            int id = tid + it * 256;
            int cl = id & 127, h = id >> 7;   // h 0..7
            int cg = cl + 128 * h2;
            size_t gidx = ((size_t)(b * CDIM + cg)) * NPIX + (size_t)(wh * 8 + h) * HH + ww * 8;
            fx4 x0 = *(const fx4*)(xlo + gidx);
            fx4 x1 = *(const fx4*)(xlo + gidx + 4);
            fx4 r0, r1;
#pragma unroll
            for (int jj = 0; jj < 4; ++jj) {
                r0[jj] = bf2f(Os[(h * 8 + jj)     * 136 + cl]) + x0[jj];
                r1[jj] = bf2f(Os[(h * 8 + 4 + jj) * 136 + cl]) + x1[jj];
            }
            *(fx4*)(outp + gidx)     = r0;
            *(fx4*)(outp + gidx + 4) = r1;
        }
    }
}

extern "C" void kernel_launch(void* const* d_in, const int* in_sizes, int n_in,
                              void* d_out, int out_size, void* d_ws, size_t ws_size,
                              hipStream_t stream) {
    const float* xlo = (const float*)d_in[0];
    const float* xhi = (const float*)d_in[1];
    const float* wqp = (const float*)d_in[2];
    const float* wkp = (const float*)d_in[3];
    const float* gq  = (const float*)d_in[4];
    const float* bq  = (const float*)d_in[5];
    const float* gk  = (const float*)d_in[6];
    const float* bk  = (const float*)d_in[7];
    float* outp = (float*)d_out;
    char* ws = (char*)d_ws;
    size_t SZB = (size_t)NB * NPIX * CDIM * 2;   // 64 MB per bf16 tensor
    short* qt    = (short*)(ws);
    short* kt    = (short*)(ws + SZB);
    float* stats = (float*)(ws + 2 * SZB);
    float* scale = (float*)(ws + 2 * SZB + 4096);
    float* shift = (float*)(ws + 2 * SZB + 4096 + 16384);
    short* WB    = (short*)(ws + 2 * SZB + 4096 + 32768);

    hipMemsetAsync(stats, 0, 4096, stream);
    kW<<<dim3(8, 2), dim3(256), 0, stream>>>(wqp, wkp, WB);
    kG<<<dim3(128, 16), dim3(256), 0, stream>>>(xlo, xhi, WB, qt, kt, stats);
    kS<<<dim3(16), dim3(256), 0, stream>>>(stats, gq, bq, gk, bk, scale, shift);
    kA<<<dim3(2048), dim3(256), 0, stream>>>(qt, kt, scale, shift, xlo, outp);
}